// Round 2
// baseline (151.852 us; speedup 1.0000x reference)
//
#include <hip/hip_runtime.h>
#include <math.h>

// Problem constants
#define NVOX  1048576   // voxels per BC slice (64*128*128)
#define NSLC  4         // dst0, dst1, ref0, ref1
#define MFINE 2048      // fine histogram bins over [0,1]
#define BINS  32
#define HIST_BLOCKS 1024   // 256 per slice
#define APPLY_BLOCKS 1024  // 2 slices * 1M voxels / (256 thr * 8 vox)

// d_ws layout (bytes):
//   [0, 32768)      : uint32 fine[4][2048]   (zeroed by memset node)
//   [32768, 32772)  : uint32 done ticket     (zeroed by memset node)
//   [32832, 33088)  : float  gt[2][32] = g_k * table_k (per dst slice)
//   [33088, 33216)  : float  gd[32]    = g_k = exp(-k^2/50)

// ---------------------------------------------------------------------------
// K1: fine hard histogram (1024 blocks x 256 thr, 4 float4 = 16 voxels/thr),
// then the LAST block (atomic ticket) computes the soft histogram by
// convolving fine counts with f(d) = sig(5(d+.5)) - sig(5(d-.5)) truncated to
// |d| <= 4.5 (tail < 2e-11), then cdf + argmin matching table -> gt, gd.
// ---------------------------------------------------------------------------
__global__ __launch_bounds__(256) void hist_kernel(const float4* __restrict__ dst4,
                                                   const float4* __restrict__ ref4,
                                                   unsigned int* __restrict__ fine,
                                                   unsigned int* __restrict__ done,
                                                   float* __restrict__ gt,
                                                   float* __restrict__ gd) {
    // fl doubles as the block-local histogram (first 2048) in phase 1,
    // and as the full 4-slice fine-hist copy in the last-block phase.
    __shared__ unsigned int fl[NSLC * MFINE];   // 32 KB
    __shared__ float soft_s[NSLC][BINS];
    __shared__ float cdf[NSLC][BINS];
    __shared__ unsigned int is_last;

    const int t  = threadIdx.x;
    const int b  = blockIdx.x;
    const int s  = b >> 8;     // slice 0..3
    const int ib = b & 255;

    unsigned int* h = fl;      // 2048-bin local hist
    for (int i = t; i < MFINE; i += 256) h[i] = 0;
    __syncthreads();

    const float4* src = (s < 2) ? (dst4 + s * (NVOX / 4))
                                : (ref4 + (s - 2) * (NVOX / 4));
    const int base = ib * 1024;   // 1024 float4 per block

    #pragma unroll
    for (int j = 0; j < 4; ++j) {
        float4 v = src[base + j * 256 + t];
        int m0 = min(max((int)(v.x * (float)MFINE), 0), MFINE - 1);
        int m1 = min(max((int)(v.y * (float)MFINE), 0), MFINE - 1);
        int m2 = min(max((int)(v.z * (float)MFINE), 0), MFINE - 1);
        int m3 = min(max((int)(v.w * (float)MFINE), 0), MFINE - 1);
        atomicAdd(&h[m0], 1u);
        atomicAdd(&h[m1], 1u);
        atomicAdd(&h[m2], 1u);
        atomicAdd(&h[m3], 1u);
    }
    __syncthreads();

    for (int i = t; i < MFINE; i += 256) {
        unsigned int c = h[i];
        if (c) atomicAdd(&fine[s * MFINE + i], c);
    }
    __syncthreads();   // drains vmcnt: this block's global atomics are performed

    if (t == 0)
        is_last = (atomicAdd(done, 1u) == HIST_BLOCKS - 1) ? 1u : 0u;
    __syncthreads();
    if (!is_last) return;

    // ---- last block only: coherent copy of all fine hists into LDS ----
    for (int i = t; i < NSLC * MFINE; i += 256)
        fl[i] = __hip_atomic_load(&fine[i], __ATOMIC_RELAXED,
                                  __HIP_MEMORY_SCOPE_AGENT);
    __syncthreads();

    // ---- soft histogram: 128 (slice,bin) pairs x 2 half-threads ----
    {
        const int pair = t >> 1, half = t & 1;
        const int s2 = pair >> 5, c = pair & 31;
        const float fc = (float)c;
        int i0 = (int)ceilf((fc - 4.5f) * ((float)MFINE / 31.0f) - 0.5f);
        int i1 = (int)floorf((fc + 4.5f) * ((float)MFINE / 31.0f) - 0.5f);
        if (i0 < 0) i0 = 0;
        if (i1 > MFINE - 1) i1 = MFINE - 1;
        float acc = 0.f;
        for (int i = i0 + half; i <= i1; i += 2) {
            unsigned int cnt = fl[s2 * MFINE + i];
            if (cnt) {
                float d  = (i + 0.5f) * (31.0f / (float)MFINE) - fc;
                float fa = 1.f / (1.f + __expf(-5.f * (d + 0.5f)));
                float fb = 1.f / (1.f + __expf(-5.f * (d - 0.5f)));
                acc += (float)cnt * (fa - fb);
            }
        }
        acc += __shfl_xor(acc, 1, 64);
        if (half == 0) soft_s[s2][c] = acc;
    }
    __syncthreads();

    // ---- normalize + cumsum ----
    if (t < NSLC) {
        float sum = 0.f;
        for (int c = 0; c < BINS; ++c) sum += soft_s[t][c];
        float inv = 1.f / fmaxf(sum, 1e-12f);
        float run = 0.f;
        for (int c = 0; c < BINS; ++c) {
            run += soft_s[t][c];
            cdf[t][c] = run * inv;
        }
    }
    __syncthreads();

    // ---- argmin matching table; emit g_k and g_k * table_k ----
    if (t < 64) {
        const int s2 = t >> 5, i = t & 31;
        float v = cdf[s2][i];
        int best = 0;
        float bd = fabsf(v - cdf[s2 + 2][0]);
        #pragma unroll
        for (int j = 1; j < BINS; ++j) {
            float dj = fabsf(v - cdf[s2 + 2][j]);
            if (dj < bd) { bd = dj; best = j; }   // strict < keeps lowest index
        }
        float g = __expf(-(float)(i * i) * (1.0f / 50.0f));
        gt[s2 * BINS + i] = g * (float)best;
        if (s2 == 0) gd[i] = g;
    }
}

// ---------------------------------------------------------------------------
// K2: apply. softmax(-(y-k)^2/50) factorized: w_k ∝ r^k * g_k, r = e^{y/25}.
// 1024 blocks x 256 thr, 8 voxels/thread; k-loop outside the voxel set so
// each LDS float2 read is amortized over 8 voxels (24 FMA per ds_read_b64).
// ---------------------------------------------------------------------------
__global__ __launch_bounds__(256) void apply_kernel(const float4* __restrict__ dst4,
                                                    const float* __restrict__ gt,
                                                    const float* __restrict__ gd,
                                                    float4* __restrict__ out4) {
    __shared__ float2 sgg[BINS];   // (gd_k, gt_k) for this slice
    const int t  = threadIdx.x;
    const int b  = blockIdx.x;
    const int s  = b >> 9;
    const int ib = b & 511;

    if (t < BINS) sgg[t] = make_float2(gd[t], gt[s * BINS + t]);
    __syncthreads();

    const int base = s * (NVOX / 4) + ib * 512;

    float4 v[2];
    #pragma unroll
    for (int j = 0; j < 2; ++j) v[j] = dst4[base + j * 256 + t];
    float* x = (float*)v;   // 8 voxel values

    float r[8], u[8], num[8], den[8];
    #pragma unroll
    for (int i = 0; i < 8; ++i) {
        float y = x[i] * 31.0f;
        r[i] = __expf(y * (1.0f / 25.0f));
        u[i] = 1.0f;
        num[i] = 0.0f;
        den[i] = 0.0f;
    }

    #pragma unroll
    for (int k = 0; k < BINS; ++k) {
        float2 gg = sgg[k];
        #pragma unroll
        for (int i = 0; i < 8; ++i) {
            num[i] = fmaf(u[i], gg.y, num[i]);
            den[i] = fmaf(u[i], gg.x, den[i]);
            u[i] *= r[i];
        }
    }

    #pragma unroll
    for (int i = 0; i < 8; ++i) {
        x[i] = num[i] * __builtin_amdgcn_rcpf(den[i]) * (1.0f / 31.0f);
    }
    #pragma unroll
    for (int j = 0; j < 2; ++j) out4[base + j * 256 + t] = v[j];
}

// ---------------------------------------------------------------------------
extern "C" void kernel_launch(void* const* d_in, const int* in_sizes, int n_in,
                              void* d_out, int out_size, void* d_ws, size_t ws_size,
                              hipStream_t stream) {
    const float4* dst4 = (const float4*)d_in[0];
    const float4* ref4 = (const float4*)d_in[1];
    float4* out4 = (float4*)d_out;

    unsigned int* fine = (unsigned int*)d_ws;
    unsigned int* done = (unsigned int*)((char*)d_ws + 32768);
    float* gt = (float*)((char*)d_ws + 32832);
    float* gd = (float*)((char*)d_ws + 33088);

    // zero fine hists + ticket (d_ws is poisoned 0xAA before every call)
    hipMemsetAsync(d_ws, 0, 32772, stream);

    hipLaunchKernelGGL(hist_kernel,  dim3(HIST_BLOCKS),  dim3(256), 0, stream,
                       dst4, ref4, fine, done, gt, gd);
    hipLaunchKernelGGL(apply_kernel, dim3(APPLY_BLOCKS), dim3(256), 0, stream,
                       dst4, gt, gd, out4);
}

// Round 3
// 85.078 us; speedup vs baseline: 1.7849x; 1.7849x over previous
//
#include <hip/hip_runtime.h>
#include <math.h>

// Problem constants
#define NVOX  1048576      // voxels per BC slice (64*128*128)
#define NSLC  4            // dst0, dst1, ref0, ref1
#define MFINE 2048         // fine histogram bins over [0,1]
#define BINS  32
#define HIST_BLOCKS 512    // 128 per slice, 32 voxels/thread
#define APPLY_BLOCKS 1024  // 2 slices * 1M voxels / (256 thr * 8 vox)
#define NLUT  2048         // output-function LUT entries per dst slice

// d_ws layout (bytes), all regions written before read (no memset needed):
//   [0, 65536)       : float partial[512][32]   per-block soft-hist partials
//   [65536, 81920)   : float lut[2][2048]       voxel->output function LUT

// ---------------------------------------------------------------------------
// K1: private fine histogram per block (LDS atomics), then each block
// convolves its OWN hist with f(d) = sig(5(d+.5)) - sig(5(d-.5)) truncated to
// |d| <= 4.5 (tail < 2e-11), using the 1-exp identity
//   f = E*c1 / (1 + E*c2 + E^2),  E = e^{5d}, c1 = e^2.5-e^-2.5, c2 = e^2.5+e^-2.5
// and writes a non-atomic 32-float partial. Conv is linear, so
// sum-of-partials == conv-of-total. No global atomics, no serial tail.
// ---------------------------------------------------------------------------
__global__ __launch_bounds__(256) void hist_kernel(const float4* __restrict__ dst4,
                                                   const float4* __restrict__ ref4,
                                                   float* __restrict__ partial) {
    __shared__ unsigned int h[MFINE];   // 8 KB
    const int t  = threadIdx.x;
    const int b  = blockIdx.x;
    const int s  = b >> 7;      // slice 0..3
    const int ib = b & 127;

    for (int i = t; i < MFINE; i += 256) h[i] = 0;
    __syncthreads();

    const float4* src = (s < 2) ? (dst4 + s * (NVOX / 4))
                                : (ref4 + (s - 2) * (NVOX / 4));
    const int base = ib * 2048;   // 2048 float4 per block

    #pragma unroll
    for (int j = 0; j < 8; ++j) {
        float4 v = src[base + j * 256 + t];
        int m0 = min(max((int)(v.x * (float)MFINE), 0), MFINE - 1);
        int m1 = min(max((int)(v.y * (float)MFINE), 0), MFINE - 1);
        int m2 = min(max((int)(v.z * (float)MFINE), 0), MFINE - 1);
        int m3 = min(max((int)(v.w * (float)MFINE), 0), MFINE - 1);
        atomicAdd(&h[m0], 1u);
        atomicAdd(&h[m1], 1u);
        atomicAdd(&h[m2], 1u);
        atomicAdd(&h[m3], 1u);
    }
    __syncthreads();

    // ---- per-block conv: 32 bins x 8 lanes each ----
    const int c = t >> 3;       // soft bin 0..31
    const int j = t & 7;
    const float fc = (float)c;
    const float DY = 31.0f / (float)MFINE;     // fine-bin width in y units
    const float c1 = 12.1825190f;              // e^2.5 - e^-2.5
    const float c2 = 12.3467369f;              // e^2.5 + e^-2.5

    int i0 = (int)ceilf((fc - 4.5f) * ((float)MFINE / 31.0f) - 0.5f);
    int i1 = (int)floorf((fc + 4.5f) * ((float)MFINE / 31.0f) - 0.5f);
    if (i0 < 0) i0 = 0;
    if (i1 > MFINE - 1) i1 = MFINE - 1;

    float acc = 0.f;
    for (int i = i0 + j; i <= i1; i += 8) {
        float cnt = (float)h[i];
        float d   = fmaf((float)i, DY, 0.5f * DY - fc);
        float E   = __expf(5.0f * d);
        float den = fmaf(E, c2, fmaf(E, E, 1.0f));
        acc = fmaf(cnt * E, c1 * __builtin_amdgcn_rcpf(den), acc);
    }
    acc += __shfl_xor(acc, 1, 64);
    acc += __shfl_xor(acc, 2, 64);
    acc += __shfl_xor(acc, 4, 64);
    if (j == 0) partial[b * BINS + c] = acc;
}

// ---------------------------------------------------------------------------
// K2: 1 block x 1024 thr. Reduce partials -> soft hist; shuffle prefix-sum
// cumsum + normalize -> cdf; argmin matching table; build 2048-entry LUT of
// the full voxel->output function per dst slice.
// ---------------------------------------------------------------------------
__global__ __launch_bounds__(1024) void table_kernel(const float* __restrict__ partial,
                                                     float* __restrict__ lut) {
    __shared__ float softS[NSLC][BINS];
    __shared__ float cdfS[NSLC][BINS];
    __shared__ float gS[BINS];        // exp(-k^2/50)
    __shared__ float gtS[2][BINS];    // g_k * table_k
    const int t = threadIdx.x;

    // ---- reduce 128 partials per (slice,bin): 128 pairs x 8 lanes ----
    {
        const int p = t >> 3, j = t & 7;
        const int s = p >> 5, c = p & 31;
        float acc = 0.f;
        #pragma unroll
        for (int m = 0; m < 16; ++m)
            acc += partial[(s * 128 + j + 8 * m) * BINS + c];
        acc += __shfl_xor(acc, 1, 64);
        acc += __shfl_xor(acc, 2, 64);
        acc += __shfl_xor(acc, 4, 64);
        if (j == 0) softS[s][c] = acc;
    }
    __syncthreads();

    // ---- cumsum + normalize: one wave per slice, shuffle prefix scan ----
    if (t < 256) {
        const int s = t >> 6, lane = t & 63;
        float v = (lane < BINS) ? softS[s][lane] : 0.f;
        #pragma unroll
        for (int off = 1; off < BINS; off <<= 1) {
            float w = __shfl_up(v, off, 64);
            if (lane >= off) v += w;
        }
        float total = __shfl(v, BINS - 1, 64);
        if (lane < BINS) cdfS[s][lane] = v / fmaxf(total, 1e-12f);
    }
    __syncthreads();

    // ---- argmin matching table ----
    if (t < 64) {
        const int s = t >> 5, i = t & 31;
        float v = cdfS[s][i];
        int best = 0;
        float bd = fabsf(v - cdfS[s + 2][0]);
        #pragma unroll
        for (int k = 1; k < BINS; ++k) {
            float dk = fabsf(v - cdfS[s + 2][k]);
            if (dk < bd) { bd = dk; best = k; }   // strict < keeps lowest index
        }
        float g = __expf(-(float)(i * i) * (1.0f / 50.0f));
        gtS[s][i] = g * (float)best;
        if (s == 0) gS[i] = g;
    }
    __syncthreads();

    // ---- LUT: out(x) = (sum_k u_k g_k t_k)/(sum_k u_k g_k)/31, u_k = r^k,
    //      r = e^{y/25}, y = x*31, at x = idx/2047 ----
    for (int e = t; e < 2 * NLUT; e += 1024) {
        const int s = e >> 11, idx = e & (NLUT - 1);
        float y = (float)idx * (31.0f / (float)(NLUT - 1));
        float r = __expf(y * (1.0f / 25.0f));
        float u = 1.f, num = 0.f, den = 0.f;
        #pragma unroll
        for (int k = 0; k < BINS; ++k) {
            num = fmaf(u, gtS[s][k], num);
            den = fmaf(u, gS[k], den);
            u *= r;
        }
        lut[s * NLUT + idx] = num * __builtin_amdgcn_rcpf(den) * (1.0f / 31.0f);
    }
}

// ---------------------------------------------------------------------------
// K3: apply = LDS LUT lookup + linear interp. 1024 blocks x 256 thr x 8 vox.
// ---------------------------------------------------------------------------
__global__ __launch_bounds__(256) void apply_kernel(const float4* __restrict__ dst4,
                                                    const float* __restrict__ lut,
                                                    float4* __restrict__ out4) {
    __shared__ float slut[NLUT];   // 8 KB
    const int t  = threadIdx.x;
    const int b  = blockIdx.x;
    const int s  = b >> 9;
    const int ib = b & 511;

    for (int i = t; i < NLUT; i += 256) slut[i] = lut[s * NLUT + i];
    __syncthreads();

    const int base = s * (NVOX / 4) + ib * 512;

    float4 v[2];
    #pragma unroll
    for (int j = 0; j < 2; ++j) v[j] = dst4[base + j * 256 + t];
    float* x = (float*)v;   // 8 voxel values

    #pragma unroll
    for (int i = 0; i < 8; ++i) {
        float p = x[i] * (float)(NLUT - 1);
        p = fminf(fmaxf(p, 0.f), (float)(NLUT - 1) - 1.0f);
        int   ix = (int)p;
        float fr = p - (float)ix;
        float lo = slut[ix], hi = slut[ix + 1];
        x[i] = fmaf(fr, hi - lo, lo);
    }
    #pragma unroll
    for (int j = 0; j < 2; ++j) out4[base + j * 256 + t] = v[j];
}

// ---------------------------------------------------------------------------
extern "C" void kernel_launch(void* const* d_in, const int* in_sizes, int n_in,
                              void* d_out, int out_size, void* d_ws, size_t ws_size,
                              hipStream_t stream) {
    const float4* dst4 = (const float4*)d_in[0];
    const float4* ref4 = (const float4*)d_in[1];
    float4* out4 = (float4*)d_out;

    float* partial = (float*)d_ws;
    float* lut     = (float*)((char*)d_ws + 65536);

    hipLaunchKernelGGL(hist_kernel,  dim3(HIST_BLOCKS),  dim3(256), 0, stream,
                       dst4, ref4, partial);
    hipLaunchKernelGGL(table_kernel, dim3(1),            dim3(1024), 0, stream,
                       partial, lut);
    hipLaunchKernelGGL(apply_kernel, dim3(APPLY_BLOCKS), dim3(256), 0, stream,
                       dst4, lut, out4);
}

// Round 4
// 83.071 us; speedup vs baseline: 1.8280x; 1.0242x over previous
//
#include <hip/hip_runtime.h>
#include <math.h>

// Problem constants
#define NVOX  1048576      // voxels per BC slice (64*128*128)
#define NSLC  4            // dst0, dst1, ref0, ref1
#define MFINE 2048         // fine histogram bins over [0,1]
#define BINS  32
#define PB    256          // hist blocks per slice
#define HIST_BLOCKS  (NSLC * PB)   // 1024
#define APPLY_BLOCKS 512           // 2 slices * 1M voxels / (256 thr * 16 vox)
#define NLUT  2048

// d_ws layout (bytes), all regions written before read (no memset needed):
//   [0, 131072) : float partial[4*32][256]  soft-hist partials, [slice_bin][block]

// ---------------------------------------------------------------------------
// K1: private fine histogram per block (LDS atomics), then each block
// convolves its OWN hist with f(d) = sig(5(d+.5)) - sig(5(d-.5)) truncated to
// |d| <= 4.5 (tail < 2e-11), via the 1-exp identity
//   f = E*c1 / (1 + E*c2 + E^2),  E = e^{5d}, c1 = e^2.5-e^-2.5, c2 = e^2.5+e^-2.5
// Conv is linear, so sum-of-partials == conv-of-total. Partials are written
// transposed ([slice_bin][block]) for coalesced reduction in K2.
// ---------------------------------------------------------------------------
__global__ __launch_bounds__(256) void hist_kernel(const float4* __restrict__ dst4,
                                                   const float4* __restrict__ ref4,
                                                   float* __restrict__ partial) {
    __shared__ unsigned int h[MFINE];   // 8 KB
    const int t  = threadIdx.x;
    const int b  = blockIdx.x;
    const int s  = b >> 8;      // slice 0..3
    const int ib = b & 255;

    for (int i = t; i < MFINE; i += 256) h[i] = 0;
    __syncthreads();

    const float4* src = (s < 2) ? (dst4 + s * (NVOX / 4))
                                : (ref4 + (s - 2) * (NVOX / 4));
    const int base = ib * 1024;   // 1024 float4 per block

    #pragma unroll
    for (int j = 0; j < 4; ++j) {
        float4 v = src[base + j * 256 + t];
        int m0 = min(max((int)(v.x * (float)MFINE), 0), MFINE - 1);
        int m1 = min(max((int)(v.y * (float)MFINE), 0), MFINE - 1);
        int m2 = min(max((int)(v.z * (float)MFINE), 0), MFINE - 1);
        int m3 = min(max((int)(v.w * (float)MFINE), 0), MFINE - 1);
        atomicAdd(&h[m0], 1u);
        atomicAdd(&h[m1], 1u);
        atomicAdd(&h[m2], 1u);
        atomicAdd(&h[m3], 1u);
    }
    __syncthreads();

    // ---- per-block conv: 32 bins x 8 lanes each ----
    const int c = t >> 3;       // soft bin 0..31
    const int j = t & 7;
    const float fc = (float)c;
    const float DY = 31.0f / (float)MFINE;     // fine-bin width in y units
    const float c1 = 12.1825190f;              // e^2.5 - e^-2.5
    const float c2 = 12.3467369f;              // e^2.5 + e^-2.5

    int i0 = (int)ceilf((fc - 4.5f) * ((float)MFINE / 31.0f) - 0.5f);
    int i1 = (int)floorf((fc + 4.5f) * ((float)MFINE / 31.0f) - 0.5f);
    if (i0 < 0) i0 = 0;
    if (i1 > MFINE - 1) i1 = MFINE - 1;

    float acc = 0.f;
    for (int i = i0 + j; i <= i1; i += 8) {
        float cnt = (float)h[i];
        float d   = fmaf((float)i, DY, 0.5f * DY - fc);
        float E   = __expf(5.0f * d);
        float den = fmaf(E, c2, fmaf(E, E, 1.0f));
        acc = fmaf(cnt * E, c1 * __builtin_amdgcn_rcpf(den), acc);
    }
    acc += __shfl_xor(acc, 1, 64);
    acc += __shfl_xor(acc, 2, 64);
    acc += __shfl_xor(acc, 4, 64);
    if (j == 0) partial[(s * BINS + c) * PB + ib] = acc;
}

// ---------------------------------------------------------------------------
// K2: fused table + apply. Every block redundantly (in parallel) reduces the
// partials for its dst slice + matching ref slice (32 KB, L2-resident),
// does segmented shuffle cumsum -> cdf, argmin matching table, builds a
// 2048-entry LUT of the full voxel->output function in LDS, then applies it
// to 16 voxels/thread with linear interpolation.
// ---------------------------------------------------------------------------
__global__ __launch_bounds__(256) void apply_kernel(const float4* __restrict__ dst4,
                                                    const float* __restrict__ partial,
                                                    float4* __restrict__ out4) {
    __shared__ float slut[NLUT];     // 8 KB
    __shared__ float softS[64];      // [0,32) dst bins, [32,64) ref bins
    __shared__ float cdfS[64];
    __shared__ float gS[BINS];       // exp(-k^2/50)
    __shared__ float gtS[BINS];      // g_k * table_k
    const int t  = threadIdx.x;
    const int b  = blockIdx.x;
    const int s  = b >> 8;           // dst slice 0..1
    const int ib = b & 255;

    // ---- reduce partials: 64 rows x 4 lanes, 16 float4 loads per thread ----
    {
        const int r = t >> 2, j = t & 3;
        const int grow = (r < 32) ? (s * BINS + r) : ((2 + s) * BINS + (r - 32));
        const float4* prow = (const float4*)(partial + grow * PB);
        float4 a4 = make_float4(0.f, 0.f, 0.f, 0.f);
        #pragma unroll
        for (int m = 0; m < 16; ++m) {
            float4 p = prow[j + 4 * m];
            a4.x += p.x; a4.y += p.y; a4.z += p.z; a4.w += p.w;
        }
        float acc = (a4.x + a4.y) + (a4.z + a4.w);
        acc += __shfl_xor(acc, 1, 64);
        acc += __shfl_xor(acc, 2, 64);
        if (j == 0) softS[r] = acc;
    }
    __syncthreads();

    // ---- segmented (width-32) shuffle prefix-sum + normalize -> cdf ----
    if (t < 64) {
        float v = softS[t];
        #pragma unroll
        for (int off = 1; off < BINS; off <<= 1) {
            float w = __shfl_up(v, off, 32);
            if ((t & 31) >= off) v += w;
        }
        float total = __shfl(v, 31, 32);
        cdfS[t] = v / fmaxf(total, 1e-12f);
    }
    __syncthreads();

    // ---- argmin matching table ----
    if (t < 32) {
        float v = cdfS[t];
        int best = 0;
        float bd = fabsf(v - cdfS[32]);
        #pragma unroll
        for (int k = 1; k < BINS; ++k) {
            float dk = fabsf(v - cdfS[32 + k]);
            if (dk < bd) { bd = dk; best = k; }   // strict < keeps lowest index
        }
        float g = __expf(-(float)(t * t) * (1.0f / 50.0f));
        gtS[t] = g * (float)best;
        gS[t]  = g;
    }
    __syncthreads();

    // ---- LUT: out(x) = (Σ_k u_k g_k t_k)/(Σ_k u_k g_k)/31, u_k = r^k,
    //      r = e^{y/25}, y = x*31, sampled at x = idx/2047 ----
    for (int e = t; e < NLUT; e += 256) {
        float y = (float)e * (31.0f / (float)(NLUT - 1));
        float r = __expf(y * (1.0f / 25.0f));
        float u = 1.f, num = 0.f, den = 0.f;
        #pragma unroll
        for (int k = 0; k < BINS; ++k) {
            num = fmaf(u, gtS[k], num);
            den = fmaf(u, gS[k], den);
            u *= r;
        }
        slut[e] = num * __builtin_amdgcn_rcpf(den) * (1.0f / 31.0f);
    }
    __syncthreads();

    // ---- apply: 16 voxels/thread via LUT + linear interp ----
    const int base = s * (NVOX / 4) + ib * 1024;

    float4 v[4];
    #pragma unroll
    for (int j = 0; j < 4; ++j) v[j] = dst4[base + j * 256 + t];
    float* x = (float*)v;

    #pragma unroll
    for (int i = 0; i < 16; ++i) {
        float p = x[i] * (float)(NLUT - 1);
        p = fminf(fmaxf(p, 0.f), (float)(NLUT - 1) - 1.0f);
        int   ix = (int)p;
        float fr = p - (float)ix;
        float lo = slut[ix], hi = slut[ix + 1];
        x[i] = fmaf(fr, hi - lo, lo);
    }
    #pragma unroll
    for (int j = 0; j < 4; ++j) out4[base + j * 256 + t] = v[j];
}

// ---------------------------------------------------------------------------
extern "C" void kernel_launch(void* const* d_in, const int* in_sizes, int n_in,
                              void* d_out, int out_size, void* d_ws, size_t ws_size,
                              hipStream_t stream) {
    const float4* dst4 = (const float4*)d_in[0];
    const float4* ref4 = (const float4*)d_in[1];
    float4* out4 = (float4*)d_out;
    float* partial = (float*)d_ws;

    hipLaunchKernelGGL(hist_kernel,  dim3(HIST_BLOCKS),  dim3(256), 0, stream,
                       dst4, ref4, partial);
    hipLaunchKernelGGL(apply_kernel, dim3(APPLY_BLOCKS), dim3(256), 0, stream,
                       dst4, partial, out4);
}